// Round 5
// baseline (159.074 us; speedup 1.0000x reference)
//
#include <hip/hip_runtime.h>
#include <math.h>

// NetVLAD clustering layer, f32, MI355X.
// x:[16,256,1500], centroids:[64,256], lin_w:[66,256], lin_b:[66]
// out: [16, 64*256] f32
//
// R5: broadcast-amortized tiles + occupancy + atomic K-reduction.
//  k1: Lpart[ks<2][u][c<66][t] logits partials. 512-thr blocks, 8 waves,
//      lanes 32t x 2c, Tt=4 (contiguous -> float4 X loads), Tc=4(+ghost).
//      W-half in LDS (broadcast b128, 2 distinct addrs/instr). 384 blocks.
//  k2: fused softmax + aggregation. t-chunk 64, 384 blocks, 4 waves.
//      a lives only in LDS. GEMM lanes 32f x 2c, Tf=8 x Tc=8.
//      Results accumulated with global f32 atomicAdd into comp_acc/asum_acc
//      (4 MB, L2-resident; zeroed by hipMemsetAsync).
//  k3: comp = comp_acc - asum*centroid; intra-normalize rows.
//  k4: global L2 normalize.

#define NU 16
#define NF 256
#define NT 1500
#define NC 64
#define NCG 66
#define EPSN 1e-12f

// ---------------- K1: logit partials ----------------
// grid (16 u, 12 tt, 2 ks), block 512 (8 waves).
__global__ __launch_bounds__(512, 4) void k1_logits(
        const float* __restrict__ x, const float* __restrict__ lin_w,
        float* __restrict__ Lpart) {
    const int u  = blockIdx.x;
    const int t0 = blockIdx.y * 128;
    const int ks = blockIdx.z;
    const int tid  = threadIdx.x;
    const int lane = tid & 63;
    const int wave = tid >> 6;          // 0..7
    const int tl   = lane & 31;
    const int cl   = lane >> 5;         // 0..1

    __shared__ float Ws[NCG][132];      // W k-half, stride 132 floats

    for (int idx = tid; idx < NCG * 32; idx += 512) {
        const int row = idx >> 5, q = idx & 31;
        *(float4*)&Ws[row][q * 4] = *(const float4*)(lin_w + row * NF + ks * 128 + q * 4);
    }
    __syncthreads();

    const int nTc = (wave == 0) ? 5 : 4;        // wave 0 also does ghost c=64+cl
    const int tb  = t0 + 4 * tl;                // 4 contiguous t per thread
    const int tbc = (tb + 3 < NT) ? tb : (NT - 4);
    const float* xb = x + (u * NF + ks * 128) * NT;

    float acc[5][4];                            // [c_j][t_i]
    #pragma unroll
    for (int j = 0; j < 5; ++j)
        #pragma unroll
        for (int i = 0; i < 4; ++i) acc[j][i] = 0.0f;

    #pragma unroll 2
    for (int kq = 0; kq < 32; ++kq) {
        float4 xv[4];
        #pragma unroll
        for (int e = 0; e < 4; ++e)             // k = kq*4+e; f4 over t (coalesced)
            xv[e] = *(const float4*)(xb + (kq * 4 + e) * NT + tbc);
        #pragma unroll
        for (int j = 0; j < 5; ++j) {
            if (j < nTc) {
                const int c = (j < 4) ? (8 * wave + cl * 4 + j) : (64 + cl);
                const float4 wv = *(const float4*)&Ws[c][kq * 4];   // 2-addr broadcast
                #pragma unroll
                for (int i = 0; i < 4; ++i) {
                    acc[j][i] += wv.x * (&xv[0].x)[i] + wv.y * (&xv[1].x)[i]
                               + wv.z * (&xv[2].x)[i] + wv.w * (&xv[3].x)[i];
                }
            }
        }
    }

    #pragma unroll
    for (int j = 0; j < 5; ++j) {
        if (j < nTc) {
            const int c = (j < 4) ? (8 * wave + cl * 4 + j) : (64 + cl);
            float* lp = Lpart + ((ks * NU + u) * NCG + c) * NT;
            if (tb + 3 < NT) {
                *(float4*)(lp + tb) = make_float4(acc[j][0], acc[j][1], acc[j][2], acc[j][3]);
            } else {
                #pragma unroll
                for (int i = 0; i < 4; ++i)
                    if (tb + i < NT) lp[tb + i] = acc[j][i];
            }
        }
    }
}

// ---------------- K2: fused softmax + aggregation ----------------
// grid (16 u, 24 ks), block 256 (4 waves). t-chunk 64.
__global__ __launch_bounds__(256, 3) void k2_fused(
        const float* __restrict__ x, const float* __restrict__ Lpart,
        const float* __restrict__ lin_b, float* __restrict__ comp_acc,
        float* __restrict__ asum_acc) {
    const int u  = blockIdx.x;
    const int ks = blockIdx.y;
    const int t0 = ks * 64;
    const int tid  = threadIdx.x;
    const int lane = tid & 63;
    const int w    = tid >> 6;

    __shared__ float As[NC][68];        // a[c][t_local], stride 68
    __shared__ float Xs[2][NF][20];     // x chunk [f][16 t], stride 20, dbuf
    __shared__ float red[4][64];

    // ---- phase A: softmax over 66 for this block's 64 t ----
    {
        const int tl  = tid & 63;
        const int cq  = tid >> 6;               // c-quarter 0..3
        const int tA  = t0 + tl;
        const bool valid = (tA < NT);
        const int tAc = valid ? tA : (NT - 1);
        const int nr  = (cq < 2) ? 17 : 16;     // ghosts on cq 0,1

        float v[17];
        float m = -INFINITY;
        #pragma unroll
        for (int r = 0; r < 17; ++r) {
            if (r < nr) {
                const int c = (r < 16) ? (cq * 16 + r) : (64 + cq);
                const float lv = Lpart[((0 * NU + u) * NCG + c) * NT + tAc]
                               + Lpart[((1 * NU + u) * NCG + c) * NT + tAc]
                               + lin_b[c];
                v[r] = lv;
                m = fmaxf(m, lv);
            }
        }
        red[cq][tl] = m;
        __syncthreads();
        const float M = fmaxf(fmaxf(red[0][tl], red[1][tl]),
                              fmaxf(red[2][tl], red[3][tl]));
        __syncthreads();
        float s = 0.0f;
        #pragma unroll
        for (int r = 0; r < 17; ++r) {
            if (r < nr) { v[r] = __expf(v[r] - M); s += v[r]; }
        }
        red[cq][tl] = s;
        __syncthreads();
        const float S = red[0][tl] + red[1][tl] + red[2][tl] + red[3][tl];
        const float inv = valid ? (1.0f / S) : 0.0f;   // invalid t -> a = 0
        #pragma unroll
        for (int r = 0; r < 16; ++r)
            As[cq * 16 + r][tl] = v[r] * inv;
    }

    // ---- stage x chunk 0 ----
    #pragma unroll
    for (int p = 0; p < 4; ++p) {
        const int idx = p * 256 + tid;          // 1024 float4s
        const int f = idx >> 2, q = idx & 3;
        int t = t0 + q * 4;
        if (t + 3 >= NT) t = NT - 4;
        *(float4*)&Xs[0][f][q * 4] = *(const float4*)(x + (u * NF + f) * NT + t);
    }
    __syncthreads();

    // ---- GEMM: 64c x 256f x 64t ----
    const int fl  = lane & 31;
    const int cl2 = lane >> 5;
    float acc[8][8];                            // [c_i][f_j]
    #pragma unroll
    for (int i = 0; i < 8; ++i)
        #pragma unroll
        for (int j = 0; j < 8; ++j) acc[i][j] = 0.0f;

    for (int ch = 0; ch < 4; ++ch) {
        float4 pf[4];
        if (ch < 3) {                           // register prefetch chunk ch+1
            #pragma unroll
            for (int p = 0; p < 4; ++p) {
                const int idx = p * 256 + tid;
                const int f = idx >> 2, q = idx & 3;
                int t = t0 + (ch + 1) * 16 + q * 4;
                if (t + 3 >= NT) t = NT - 4;
                pf[p] = *(const float4*)(x + (u * NF + f) * NT + t);
            }
        }
        const int b = ch & 1;
        #pragma unroll
        for (int kq = 0; kq < 4; ++kq) {
            float4 xf[8], af[8];
            #pragma unroll
            for (int j = 0; j < 8; ++j)
                xf[j] = *(const float4*)&Xs[b][fl + 32 * j][kq * 4];
            #pragma unroll
            for (int i = 0; i < 8; ++i)
                af[i] = *(const float4*)&As[w * 16 + cl2 * 8 + i][ch * 16 + kq * 4];
            #pragma unroll
            for (int i = 0; i < 8; ++i)
                #pragma unroll
                for (int j = 0; j < 8; ++j)
                    acc[i][j] += af[i].x * xf[j].x + af[i].y * xf[j].y
                               + af[i].z * xf[j].z + af[i].w * xf[j].w;
        }
        if (ch < 3) {
            __syncthreads();
            #pragma unroll
            for (int p = 0; p < 4; ++p) {
                const int idx = p * 256 + tid;
                *(float4*)&Xs[(ch + 1) & 1][idx >> 2][(idx & 3) * 4] = pf[p];
            }
            __syncthreads();
        }
    }

    // ---- accumulate into global (atomic K-reduction) ----
    #pragma unroll
    for (int i = 0; i < 8; ++i) {
        const int c = w * 16 + cl2 * 8 + i;
        float* base = comp_acc + (u * NC + c) * NF;
        #pragma unroll
        for (int j = 0; j < 8; ++j)
            atomicAdd(base + fl + 32 * j, acc[i][j]);
    }

    // asum: each wave reduces its 16 c rows over the 64 local t
    #pragma unroll
    for (int i = 0; i < 16; ++i) {
        float s = As[w * 16 + i][lane];
        #pragma unroll
        for (int off = 32; off > 0; off >>= 1) s += __shfl_down(s, off, 64);
        if (lane == 0) atomicAdd(asum_acc + u * NC + w * 16 + i, s);
    }
}

// ---------------- K3: centroid term + intra-norm ----------------
// grid (64 c, 16 u), block 256 (thread = f).
__global__ __launch_bounds__(256) void k3_norm(
        const float* __restrict__ comp_acc, const float* __restrict__ asum_acc,
        const float* __restrict__ centroids, float* __restrict__ compn,
        float* __restrict__ rowsq) {
    const int c = blockIdx.x, u = blockIdx.y;
    const int tid = threadIdx.x;
    __shared__ float sbuf[4];

    const float asum = asum_acc[u * NC + c];    // uniform -> s_load
    float val = comp_acc[(u * NC + c) * NF + tid] - asum * centroids[c * NF + tid];

    float v = val * val;
    #pragma unroll
    for (int off = 32; off > 0; off >>= 1) v += __shfl_down(v, off, 64);
    if ((tid & 63) == 0) sbuf[tid >> 6] = v;
    __syncthreads();
    const float ss = sbuf[0] + sbuf[1] + sbuf[2] + sbuf[3];

    const float d = fmaxf(sqrtf(ss), EPSN);
    compn[(u * NC + c) * NF + tid] = val / d;
    if (tid == 0) rowsq[u * NC + c] = ss / (d * d);
}

// ---------------- K4: global normalize ----------------
// grid (4, 16), block 256.
__global__ __launch_bounds__(256) void k4_scale(
        const float* __restrict__ compn, const float* __restrict__ rowsq,
        float* __restrict__ out) {
    const int u = blockIdx.y;
    const int tid = threadIdx.x;
    float gss = 0.0f;
    #pragma unroll
    for (int cc = 0; cc < NC; ++cc) gss += rowsq[u * NC + cc];  // uniform
    const float inv = 1.0f / fmaxf(sqrtf(gss), EPSN);
    const int base = u * (NC * NF) + blockIdx.x * 4096;
    #pragma unroll
    for (int r = 0; r < 16; ++r) {
        const int idx = base + r * 256 + tid;
        out[idx] = compn[idx] * inv;
    }
}

// ---------------- launcher ----------------
extern "C" void kernel_launch(void* const* d_in, const int* in_sizes, int n_in,
                              void* d_out, int out_size, void* d_ws, size_t ws_size,
                              hipStream_t stream) {
    (void)in_sizes; (void)n_in; (void)out_size; (void)ws_size;
    const float* x         = (const float*)d_in[0];
    const float* centroids = (const float*)d_in[1];
    const float* lin_w     = (const float*)d_in[2];
    const float* lin_b     = (const float*)d_in[3];
    float* out = (float*)d_out;

    float* ws        = (float*)d_ws;
    float* Lpart     = ws;                                 // 2*16*66*1500 = 3,168,000 f
    float* comp_acc  = Lpart + 2 * NU * NCG * NT;          // 16*64*256    =   262,144 f
    float* asum_acc  = comp_acc + NU * NC * NF;            // 16*64        =     1,024 f
    float* compn     = asum_acc + NU * NC;                 //                  262,144 f
    float* rowsq     = compn + NU * NC * NF;               //                    1,024 f

    // zero the atomic accumulators (comp_acc + asum_acc are contiguous)
    hipMemsetAsync(comp_acc, 0, (NU * NC * NF + NU * NC) * sizeof(float), stream);

    hipLaunchKernelGGL(k1_logits, dim3(NU, 12, 2), dim3(512), 0, stream, x, lin_w, Lpart);
    hipLaunchKernelGGL(k2_fused,  dim3(NU, 24),    dim3(256), 0, stream, x, Lpart, lin_b, comp_acc, asum_acc);
    hipLaunchKernelGGL(k3_norm,   dim3(NC, NU),    dim3(256), 0, stream, comp_acc, asum_acc, centroids, compn, rowsq);
    hipLaunchKernelGGL(k4_scale,  dim3(4, NU),     dim3(256), 0, stream, compn, rowsq, out);
}